// Round 3
// baseline (1967.586 us; speedup 1.0000x reference)
//
#include <hip/hip_runtime.h>
#include <cstddef>

#define LOG2E 1.4426950408889634f
#define LN2   0.6931471805599453f

typedef float    f32x2 __attribute__((ext_vector_type(2)));
typedef float    f32x4 __attribute__((ext_vector_type(4)));
typedef _Float16 half8 __attribute__((ext_vector_type(8)));

constexpr int K_    = 256;
constexpr int T_    = 2048;
constexpr int DMAX_ = 64;
constexpr int B_    = 16;

__device__ __forceinline__ float fexp2(float x) { return __builtin_amdgcn_exp2f(x); }
__device__ __forceinline__ float flog2(float x) { return __builtin_amdgcn_logf(x); }
__device__ __forceinline__ float frcp (float x) { return __builtin_amdgcn_rcpf(x); }

// cross-half (lane ^ 32) exchange on the VALU via v_permlane32_swap_b32.
// Two DISTINCT "=&v" outputs, movs inside the asm (no coalescing), s_nop pad.
// r.x + r.y is the cross-half sum regardless of swap direction; the "other
// half's value" is whichever element differs from own (equal -> either fine).
__device__ __forceinline__ f32x2 xchg32(float x) {
    float a, b;
    asm("v_mov_b32 %0, %2\n\t"
        "v_mov_b32 %1, %2\n\t"
        "s_nop 1\n\t"
        "v_permlane32_swap_b32 %0, %1"
        : "=&v"(a), "=&v"(b)
        : "v"(x));
    return (f32x2){a, b};
}

// max-reduce across a 16-lane row via DPP row_ror (VALU, no LDS pipe).
template<int CTRL>
__device__ __forceinline__ float dpp_maxf(float x) {
    int m = __builtin_amdgcn_update_dpp(0, __builtin_bit_cast(int, x), CTRL, 0xF, 0xF, true);
    return fmaxf(x, __builtin_bit_cast(float, m));
}

// 512 threads = 8 waves, 2 waves/SIMD. Wave w owns columns 32w..32w+31.
// Lane map: j = 32w + (lane&31); q = lane>>5 owns duration ages 32q+1..32q+32.
// SOFTWARE-PIPELINED step (this round's change): the duration dot is
// reassociated as  S_t = rsc_{t-1}*dotshift_{t-1} + head_t*pD[1]  where
// dotshift = dot(v, pD_shifted) is computed in the PREVIOUS iteration's
// MFMA-wait window, along with the physical shift/rescale of v. The critical
// chain per step is now only: mySmv -> rsc -> S -> p -> ds_write -> barrier ->
// ds_read -> MFMA.  Off-chain work (dotshift, 33-mul shift, alpha store,
// anchor maxes, prefetch ring) fills the MFMA/LDS wait slots.
__global__ __launch_bounds__(512)
__attribute__((amdgpu_waves_per_eu(2, 2)))
void hsmm_fwd_kernel(const float* __restrict__ logB,   // [B,T,K]
                     const float* __restrict__ pi,     // [K]
                     const float* __restrict__ A,      // [K,K]
                     const float* __restrict__ D,      // [K,DMAX]
                     float* __restrict__ out)          // [16] loglik ++ [B,T,K] alphas
{
    const int b    = blockIdx.x;
    const int tid  = threadIdx.x;
    const int w    = tid >> 6;
    const int lane = tid & 63;
    const int j    = (w << 5) | (lane & 31);   // column 0..255
    const int q    = lane >> 5;                // age half

    alignas(16) __shared__ _Float16 lds_ph[2][K_];    // p f16, ping-pong by t&1
    alignas(16) __shared__ float    lds_red[2][8];    // per-wave max a_in, ping-pong

    // ---- init: B-fragments (P = exp(A_logits), f16, MFMA B-layout) ----
    half8 Bf0[8], Bf1[8];
    {
        const int krow = (lane >> 4) * 8;
        const int n0   = (w << 5) + (lane & 15);
        #pragma unroll
        for (int kc = 0; kc < 8; ++kc) {
            #pragma unroll
            for (int jj = 0; jj < 8; ++jj) {
                const int k = kc * 32 + krow + jj;
                Bf0[kc][jj] = (_Float16)fexp2(A[(size_t)k * K_ + n0     ] * LOG2E);
                Bf1[kc][jj] = (_Float16)fexp2(A[(size_t)k * K_ + n0 + 16] * LOG2E);
            }
        }
    }
    f32x2 pDf[16];     // pD at own ages 32q+2k+1 (.x), 32q+2k+2 (.y)
    f32x2 pDf_s[16];   // pD at own ages +1 (for the shifted dot); age 65 -> 0
    {
        const float* Dj = D + (size_t)j * DMAX_ + 32 * q;
        #pragma unroll
        for (int k = 0; k < 16; ++k)
            pDf[k] = (f32x2){ fexp2(Dj[2 * k] * LOG2E), fexp2(Dj[2 * k + 1] * LOG2E) };
        #pragma unroll
        for (int k = 0; k < 16; ++k) {
            float sx = fexp2(Dj[2 * k + 1] * LOG2E);
            float sy = (k == 15) ? ((q == 0) ? fexp2(Dj[32] * LOG2E) : 0.0f)
                                 : fexp2(Dj[2 * k + 2] * LOG2E);
            pDf_s[k] = (f32x2){ sx, sy };
        }
    }
    const float pD1 = fexp2(D[(size_t)j * DMAX_] * LOG2E);   // pD[age=1], both halves

    f32x2 v[16];
    #pragma unroll
    for (int k = 0; k < 16; ++k) v[k] = (f32x2){0.0f, 0.0f};
    float mcol     = pi[j] * LOG2E;     // column anchor (base-2)
    float cumb     = 0.0f;
    float m_anchor = 0.0f;              // lag-2 block anchor

    // pipeline registers (time -1 state): v all-zero, head value 1.0 (the pi mass)
    float rsc_p   = 1.0f;   // rsc_{t-1}
    float hv      = 1.0f;   // head value v_t[1] (insert at window t)
    float hvpd    = pD1;    // hv * pD[1]
    float ds_full = 0.0f;   // dotshift over v_{t-1}, cross-half summed

    if (tid < 8) { lds_red[0][tid] = 0.0f; lds_red[1][tid] = 0.0f; }
    __syncthreads();

    const float* lb = logB + (size_t)b * T_ * K_ + j;
    float*       ao = out + 16 + (size_t)b * T_ * K_ + j;

    // depth-3 prefetch ring for the per-step emission
    float bld0 = lb[0];
    float bld1 = lb[K_];
    float bld2 = lb[2 * K_];
    int   ldoff = 3 * K_;
    int   aoff  = 0;

    #pragma unroll 2
    for (int t = 0; t < T_; ++t) {
        const int s = t & 1;
        cumb = fmaf(bld0, LOG2E, cumb);

        // scale factors (short scalar chains off the previous tail)
        const float argh = 0.5f * (cumb + mcol - m_anchor);
        const float ea   = fminf(fexp2(argh),  1.8e19f);
        const float ga   = fminf(fexp2(-argh), 1.8e19f);
        const float ea2  = ea * ea;
        const float ga2  = ga * ga;
        const float mac  = m_anchor - cumb;

        // ---- S_t from pipeline regs: ONE fma on the chain ----
        const float S = fmaf(rsc_p, ds_full, hvpd);
        float p = fminf(S * ea2, 60000.0f);     // f16-overflow clamp
        if (q == 0) lds_ph[s][j] = (_Float16)p;

        // ---- the ONE barrier: pinned so no LDS op crosses it ----
        asm volatile("s_waitcnt lgkmcnt(0)" ::: "memory");
        __builtin_amdgcn_sched_barrier(0);
        __builtin_amdgcn_s_barrier();
        __builtin_amdgcn_sched_barrier(0);

        // ---- window: globals + off-chain VALU, overlapped with MFMA waits ----
        bld0 = bld1; bld1 = bld2;
        bld2 = lb[ldoff];
        ldoff += (ldoff < (T_ - 1) * K_) ? K_ : 0;
        if (q == 0) ao[aoff] = (cumb + mcol + flog2(S)) * LN2;
        aoff += K_;

        // hoisted anchor-feed read (other ping-pong buffer)
        f32x4 r0 = ((const f32x4*)lds_red[s ^ 1])[0];
        f32x4 r1 = ((const f32x4*)lds_red[s ^ 1])[1];

        // physical v update to time t (uses prev-tail rsc_p / hv)
        f32x2 hp  = xchg32(v[15].y);
        float oth = (hp.x == v[15].y) ? hp.y : hp.x;
        float hand = oth * rsc_p;
        #pragma unroll
        for (int k = 15; k >= 1; --k) {
            v[k].y = v[k].x * rsc_p;
            v[k].x = v[k - 1].y * rsc_p;
        }
        v[0].y = v[0].x * rsc_p;
        v[0].x = (q == 0) ? hv : hand;

        // dotshift over the new v (feeds S_{t+1}; off-chain)
        f32x2 s0 = {0.f,0.f}, s1 = {0.f,0.f}, s2 = {0.f,0.f}, s3 = {0.f,0.f};
        #pragma unroll
        for (int k = 0; k < 16; k += 4) {
            s0 = __builtin_elementwise_fma(v[k + 0], pDf_s[k + 0], s0);
            s1 = __builtin_elementwise_fma(v[k + 1], pDf_s[k + 1], s1);
            s2 = __builtin_elementwise_fma(v[k + 2], pDf_s[k + 2], s2);
            s3 = __builtin_elementwise_fma(v[k + 3], pDf_s[k + 3], s3);
        }
        f32x2 sp = (s0 + s1) + (s2 + s3);
        float Sl = sp.x + sp.y;
        f32x2 pr = xchg32(Sl);
        float dsn = pr.x + pr.y;                // full dotshift, both halves

        // ---- MFMA matvec, 4 independent 4-deep chains ----
        const _Float16* pb = lds_ph[s];
        const int fo = (lane >> 4) * 8;
        const f32x4 z = {0.f,0.f,0.f,0.f};
        f32x4 d0a = z, d0b = z, d1a = z, d1b = z;
        #pragma unroll
        for (int kc = 0; kc < 4; ++kc) {
            half8 af = *(const half8*)(pb + kc * 32 + fo);
            d0a = __builtin_amdgcn_mfma_f32_16x16x32_f16(af, Bf0[kc], d0a, 0, 0, 0);
            d1a = __builtin_amdgcn_mfma_f32_16x16x32_f16(af, Bf1[kc], d1a, 0, 0, 0);
        }
        #pragma unroll
        for (int kc = 4; kc < 8; ++kc) {
            half8 af = *(const half8*)(pb + kc * 32 + fo);
            d0b = __builtin_amdgcn_mfma_f32_16x16x32_f16(af, Bf0[kc], d0b, 0, 0, 0);
            d1b = __builtin_amdgcn_mfma_f32_16x16x32_f16(af, Bf1[kc], d1b, 0, 0, 0);
        }
        float sva = d0a.x + d0b.x;              // Smv[32w + (lane&15)]
        float svb = d1a.x + d1b.x;              // Smv[32w + 16 + (lane&15)]
        float mySmv = (lane & 16) ? svb : sva;  // own column

        float m_next = fmaxf(fmaxf(fmaxf(r0.x, r0.y), fmaxf(r0.z, r0.w)),
                             fmaxf(fmaxf(r1.x, r1.y), fmaxf(r1.z, r1.w)));

        // anchor feed (off-chain): wave max via DPP row_ror
        float mx = fmaxf(sva, svb);
        mx = dpp_maxf<0x121>(mx);   // ror:1
        mx = dpp_maxf<0x122>(mx);   // ror:2
        mx = dpp_maxf<0x124>(mx);   // ror:4
        mx = dpp_maxf<0x128>(mx);   // ror:8
        if (lane == 0) lds_red[s][w] = m_anchor + flog2(fmaxf(mx, 1e-30f));

        // ---- tail: only the short scalar chain stays on the critical path ----
        float nv0 = mySmv * ga2;                // exp2(vnew - mcol)
        rsc_p = frcp(fmaxf(nv0, 1.0f));         // exp2(mcol - mnew)
        hv    = fminf(nv0, 1.0f);               // exp2(vnew - mnew)
        hvpd  = hv * pD1;
        mcol  = fmaxf(mcol, mac + flog2(mySmv)); // exact-log anchor update
        ds_full = dsn;
        if (t + 1 < T_) m_anchor = m_next;      // keep last-step anchor for loglik
    }

    // ---- loglik: lds_ph[last] holds f16 exp2(alpha_{T-1} - m_anchor) ----
    if (tid < 64) {
        const _Float16* lp = lds_ph[(T_ - 1) & 1];
        float sf = (float)lp[tid] + (float)lp[tid + 64]
                 + (float)lp[tid + 128] + (float)lp[tid + 192];
        #pragma unroll
        for (int off = 1; off < 64; off <<= 1)
            sf += __shfl_xor(sf, off, 64);
        if (tid == 0) out[b] = (m_anchor + flog2(sf)) * LN2;
    }
}

extern "C" void kernel_launch(void* const* d_in, const int* in_sizes, int n_in,
                              void* d_out, int out_size, void* d_ws, size_t ws_size,
                              hipStream_t stream) {
    const float* logB = (const float*)d_in[0];   // [16,2048,256]
    const float* pi   = (const float*)d_in[1];   // [256]
    const float* A    = (const float*)d_in[2];   // [256,256]
    const float* D    = (const float*)d_in[3];   // [256,64]
    float* out = (float*)d_out;
    (void)in_sizes; (void)n_in; (void)d_ws; (void)ws_size; (void)out_size;

    hipLaunchKernelGGL(hsmm_fwd_kernel, dim3(B_), dim3(512), 0, stream,
                       logB, pi, A, D, out);
}

// Round 4
// 1436.566 us; speedup vs baseline: 1.3696x; 1.3696x over previous
//
#include <hip/hip_runtime.h>
#include <cstddef>

#define LOG2E 1.4426950408889634f
#define LN2   0.6931471805599453f

typedef float    f32x2 __attribute__((ext_vector_type(2)));
typedef float    f32x4 __attribute__((ext_vector_type(4)));
typedef _Float16 half8 __attribute__((ext_vector_type(8)));

constexpr int K_    = 256;
constexpr int T_    = 2048;
constexpr int DMAX_ = 64;
constexpr int B_    = 16;

__device__ __forceinline__ float fexp2(float x) { return __builtin_amdgcn_exp2f(x); }
__device__ __forceinline__ float flog2(float x) { return __builtin_amdgcn_logf(x); }
__device__ __forceinline__ float frcp (float x) { return __builtin_amdgcn_rcpf(x); }

// cross-half (lane ^ 32) exchange via v_permlane32_swap_b32.
// %1 is "=&v" (early-clobber): guaranteed distinct from %2 and %0; %0 may share
// with %2 which is still correct (mov copies before swap). r.x+r.y is the
// cross-half sum either way; "other half's value" = whichever differs from own.
__device__ __forceinline__ f32x2 xchg32(float x) {
    float a = x, b;
    asm("v_mov_b32 %1, %2\n\t"
        "s_nop 1\n\t"
        "v_permlane32_swap_b32 %0, %1"
        : "+v"(a), "=&v"(b)
        : "v"(x));
    return (f32x2){a, b};
}

// max-reduce across a 16-lane row via DPP row_ror (VALU, no LDS pipe).
template<int CTRL>
__device__ __forceinline__ float dpp_maxf(float x) {
    int m = __builtin_amdgcn_update_dpp(0, __builtin_bit_cast(int, x), CTRL, 0xF, 0xF, true);
    return fmaxf(x, __builtin_bit_cast(float, m));
}

// 512 threads = 8 waves, 2 waves/SIMD. Wave w owns columns 32w..32w+31.
// Lane map: j = 32w + (lane&31); q = lane>>5 owns ages 32q+1..32q+32.
// PAIR-FRIENDLY AGE LAYOUT (this round): v[i] holds ages {32q+1+i, 32q+17+i}.
// The age shift then maps whole pairs: v[i] <- v[i-1]*rsc = v_pk_mul_f32 x15
// (vs 33 unpackable scalar muls in the old {2k+1,2k+2} layout). Dot = 16
// v_pk_fma_f32. Anchor machinery runs at HALF rate via static even/odd bodies
// (even: DPP max + lds_red write; odd: read + max3 + m_anchor update).
// Active-CU pipes were ~63% VALU + ~27% MFMA busy => throughput-bound; this
// round deletes ~35 VALU issue slots/step.
__global__ __launch_bounds__(512)
__attribute__((amdgpu_waves_per_eu(2, 2)))
void hsmm_fwd_kernel(const float* __restrict__ logB,   // [B,T,K]
                     const float* __restrict__ pi,     // [K]
                     const float* __restrict__ A,      // [K,K]
                     const float* __restrict__ D,      // [K,DMAX]
                     float* __restrict__ out)          // [16] loglik ++ [B,T,K] alphas
{
    const int b    = blockIdx.x;
    const int tid  = threadIdx.x;
    const int w    = tid >> 6;
    const int lane = tid & 63;
    const int j    = (w << 5) | (lane & 31);   // column 0..255
    const int q    = lane >> 5;                // age half

    alignas(16) __shared__ _Float16 lds_ph[2][K_];    // p f16, ping-pong by t&1
    alignas(16) __shared__ float    lds_red[8];       // per-wave max a_in (single buf)

    // ---- init: B-fragments (P = exp(A_logits), f16, MFMA B-layout) ----
    half8 Bf0[8], Bf1[8];
    {
        const int krow = (lane >> 4) * 8;
        const int n0   = (w << 5) + (lane & 15);
        #pragma unroll
        for (int kc = 0; kc < 8; ++kc) {
            #pragma unroll
            for (int jj = 0; jj < 8; ++jj) {
                const int k = kc * 32 + krow + jj;
                Bf0[kc][jj] = (_Float16)fexp2(A[(size_t)k * K_ + n0     ] * LOG2E);
                Bf1[kc][jj] = (_Float16)fexp2(A[(size_t)k * K_ + n0 + 16] * LOG2E);
            }
        }
    }
    // pD in PAIR layout: pDf[i] = {pD(age 32q+1+i), pD(age 32q+17+i)}
    f32x2 pDf[16];
    {
        const float* Dj = D + (size_t)j * DMAX_ + 32 * q;
        #pragma unroll
        for (int i = 0; i < 16; ++i)
            pDf[i] = (f32x2){ fexp2(Dj[i] * LOG2E), fexp2(Dj[16 + i] * LOG2E) };
    }

    // v[i] = values at ages {32q+1+i, 32q+17+i}
    f32x2 v[16];
    #pragma unroll
    for (int i = 0; i < 16; ++i) v[i] = (f32x2){0.0f, 0.0f};
    if (q == 0) v[0].x = 1.0f;          // age-1 holds pi mass (anchor = pi)
    float mcol     = pi[j] * LOG2E;     // column anchor (base-2)
    float cumb     = 0.0f;
    float m_anchor = 0.0f;              // block anchor (lag 2-3)

    if (tid < 8) lds_red[tid] = 0.0f;
    __syncthreads();

    const float* lb = logB + (size_t)b * T_ * K_ + j;
    float*       ao = out + 16 + (size_t)b * T_ * K_ + j;

    // depth-3 prefetch ring for the per-step emission
    float bld0 = lb[0];
    float bld1 = lb[K_];
    float bld2 = lb[2 * K_];
    int   ldoff = 3 * K_;
    int   aoff  = 0;

    // static even/odd step body (EVEN: anchor-feed write; ODD: anchor update)
    auto body = [&](int t, int s, bool even) __attribute__((always_inline)) {
        cumb = fmaf(bld0, LOG2E, cumb);

        const float argh = 0.5f * (cumb + mcol - m_anchor);
        const float ea   = fminf(fexp2(argh),  1.8e19f);
        const float ga   = fminf(fexp2(-argh), 1.8e19f);
        const float mac  = m_anchor - cumb;

        // ---- duration dot: 16 pk_fma + tree + 1 permlane ----
        f32x2 s0 = {0.f,0.f}, s1 = {0.f,0.f}, s2 = {0.f,0.f}, s3 = {0.f,0.f};
        #pragma unroll
        for (int k = 0; k < 16; k += 4) {
            s0 = __builtin_elementwise_fma(v[k + 0], pDf[k + 0], s0);
            s1 = __builtin_elementwise_fma(v[k + 1], pDf[k + 1], s1);
            s2 = __builtin_elementwise_fma(v[k + 2], pDf[k + 2], s2);
            s3 = __builtin_elementwise_fma(v[k + 3], pDf[k + 3], s3);
        }
        f32x2 sp = (s0 + s1) + (s2 + s3);
        float Sl = sp.x + sp.y;
        f32x2 pr = xchg32(Sl);
        float S  = pr.x + pr.y;                 // full sum, direction-agnostic

        float p = fminf(S * ea * ea, 60000.0f); // f16-overflow clamp
        if (q == 0) lds_ph[s][j] = (_Float16)p;

        // ---- the ONE barrier: pinned so no LDS op crosses it ----
        asm volatile("s_waitcnt lgkmcnt(0)" ::: "memory");
        __builtin_amdgcn_sched_barrier(0);
        __builtin_amdgcn_s_barrier();
        __builtin_amdgcn_sched_barrier(0);

        // globals: prefetch t+3 (in flight across barriers) + alpha store
        bld0 = bld1; bld1 = bld2;
        bld2 = lb[ldoff];
        ldoff += (ldoff < (T_ - 1) * K_) ? K_ : 0;
        if (q == 0) ao[aoff] = (cumb + mcol + flog2(S)) * LN2;
        aoff += K_;

        f32x4 r0, r1;
        if (!even) {    // hoisted anchor read (latency overlaps MFMA)
            r0 = ((const f32x4*)lds_red)[0];
            r1 = ((const f32x4*)lds_red)[1];
        }

        // ---- MFMA matvec, 4 independent 4-deep chains ----
        const _Float16* pb = lds_ph[s];
        const int fo = (lane >> 4) * 8;
        const f32x4 z = {0.f,0.f,0.f,0.f};
        f32x4 d0a = z, d0b = z, d1a = z, d1b = z;
        #pragma unroll
        for (int kc = 0; kc < 4; ++kc) {
            half8 af = *(const half8*)(pb + kc * 32 + fo);
            d0a = __builtin_amdgcn_mfma_f32_16x16x32_f16(af, Bf0[kc], d0a, 0, 0, 0);
            d1a = __builtin_amdgcn_mfma_f32_16x16x32_f16(af, Bf1[kc], d1a, 0, 0, 0);
        }
        #pragma unroll
        for (int kc = 4; kc < 8; ++kc) {
            half8 af = *(const half8*)(pb + kc * 32 + fo);
            d0b = __builtin_amdgcn_mfma_f32_16x16x32_f16(af, Bf0[kc], d0b, 0, 0, 0);
            d1b = __builtin_amdgcn_mfma_f32_16x16x32_f16(af, Bf1[kc], d1b, 0, 0, 0);
        }
        float sva = d0a.x + d0b.x;              // Smv[32w + (lane&15)]
        float svb = d1a.x + d1b.x;              // Smv[32w + 16 + (lane&15)]
        float mySmv = (lane & 16) ? svb : sva;  // own column

        float m_next = 0.0f;
        if (even) {
            // anchor feed: wave max via DPP row_ror, write lds_red (read next step)
            float mx = fmaxf(sva, svb);
            mx = dpp_maxf<0x121>(mx);   // ror:1
            mx = dpp_maxf<0x122>(mx);   // ror:2
            mx = dpp_maxf<0x124>(mx);   // ror:4
            mx = dpp_maxf<0x128>(mx);   // ror:8
            if (lane == 0) lds_red[w] = m_anchor + flog2(fmaxf(mx, 1e-30f));
        } else {
            float m1 = fmaxf(fmaxf(r0.x, r0.y), fmaxf(r0.z, r0.w));
            float m2 = fmaxf(fmaxf(r1.x, r1.y), fmaxf(r1.z, r1.w));
            m_next = fmaxf(m1, m2);
        }

        // ---- insert + PAIR shift/rescale: 15 pk_mul + 2 fixups ----
        float nv0 = mySmv * ga * ga;            // exp2(vnew - mcol)
        float rsc = frcp(fmaxf(nv0, 1.0f));     // exp2(mcol - mnew)
        float nv  = fminf(nv0, 1.0f);           // exp2(vnew - mnew)
        mcol = fmaxf(mcol, mac + flog2(mySmv)); // exact-log anchor update

        f32x2 hp  = xchg32(v[15].y);            // q0 age-32 <-> q1 age-64
        float oth = (hp.x == v[15].y) ? hp.y : hp.x;
        float p15lo = v[15].x;                  // own age 32q+16 (pre-shift)
        f32x2 rp = { rsc, rsc };
        #pragma unroll
        for (int k = 15; k >= 1; --k)
            v[k] = v[k - 1] * rp;               // ages {k+.., k+16+..} <- {k-1.., k+15..}
        v[0].y = p15lo * rsc;                   // age 32q+17 <- old 32q+16
        v[0].x = (q == 0) ? nv : oth * rsc;     // age 1 <- insert ; age 33 <- old 32

        if (!even && t + 1 < T_) m_anchor = m_next;  // keep final anchor for loglik
    };

    for (int t = 0; t < T_; t += 2) {
        body(t,     0, true );
        body(t + 1, 1, false);
    }

    // ---- loglik: lds_ph[1] holds f16 exp2(alpha_{T-1} - m_anchor) ----
    if (tid < 64) {
        const _Float16* lp = lds_ph[(T_ - 1) & 1];
        float sf = (float)lp[tid] + (float)lp[tid + 64]
                 + (float)lp[tid + 128] + (float)lp[tid + 192];
        #pragma unroll
        for (int off = 1; off < 64; off <<= 1)
            sf += __shfl_xor(sf, off, 64);
        if (tid == 0) out[b] = (m_anchor + flog2(sf)) * LN2;
    }
}

extern "C" void kernel_launch(void* const* d_in, const int* in_sizes, int n_in,
                              void* d_out, int out_size, void* d_ws, size_t ws_size,
                              hipStream_t stream) {
    const float* logB = (const float*)d_in[0];   // [16,2048,256]
    const float* pi   = (const float*)d_in[1];   // [256]
    const float* A    = (const float*)d_in[2];   // [256,256]
    const float* D    = (const float*)d_in[3];   // [256,64]
    float* out = (float*)d_out;
    (void)in_sizes; (void)n_in; (void)d_ws; (void)ws_size; (void)out_size;

    hipLaunchKernelGGL(hsmm_fwd_kernel, dim3(B_), dim3(512), 0, stream,
                       logB, pi, A, D, out);
}